// Round 11
// baseline (4361.361 us; speedup 1.0000x reference)
//
#include <hip/hip_runtime.h>
#include <stdint.h>

#define NB 128
#define NT 2048
#define NI 128
#define NH 1024
#define NO 128

typedef float f32x4 __attribute__((ext_vector_type(4)));

// ---------------------------------------------------------------------------
// W2P: pair-transpose W2 [O][H] -> W2P [H][64] of float2 {W2[j][k], W2[j+64][k]}
// ---------------------------------------------------------------------------
__global__ __launch_bounds__(256) void w2p_kernel(
    const float* __restrict__ W2, float2* __restrict__ W2P)
{
    const int idx = blockIdx.x * 256 + threadIdx.x;  // 0..65535
    const int k = idx >> 6;                          // 0..1023
    const int j = idx & 63;                          // 0..63
    W2P[idx] = make_float2(W2[(size_t)j * NH + k], W2[(size_t)(j + 64) * NH + k]);
}

// ---------------------------------------------------------------------------
// Phase A2: fused GEMM1 + LIF1 with lane = BATCH (operand flip).
// grid = 512 (2 bh x 256 ht), block = 512 = 8 waves = 8 k-sixteenths (16 k)
// of the SAME 4 h (h = ht*4..+3) and SAME 64 b (b = bh*64 + lane).
// Weights: 64 wave-uniform scalars -> SGPRs via readfirstlane (zero VGPR
// pressure - nothing for the allocator to spill, unlike R2/R3/R5/R9/R10).
// x: 4 transient dwordx4 per lane per t (short-lived, spill-proof).
// 8-way k-reduce via 2-slot-parity LDS, 1 barrier/t (R1-proven). Finisher
// wave (kq==0, rotated across SIMDs by block) runs LIF + ballot; ballot over
// lanes = b-mask for each h -> sB[t][bh][h]; bit-transposed later by snn_bitT.
// ---------------------------------------------------------------------------
__global__ __launch_bounds__(512, 4) void snn_phaseA2(
    const float* __restrict__ x, const float* __restrict__ W1,
    const float* __restrict__ b1, uint64_t* __restrict__ sB)
{
    const int bid = blockIdx.x;
    const int bh = bid >> 8;             // 0..1
    const int ht = bid & 255;            // 0..255
    const int wv = threadIdx.x >> 6;     // 0..7
    const int lane = threadIdx.x & 63;
    const int kq = __builtin_amdgcn_readfirstlane((wv + bid) & 7);  // rotated
    const int b = bh * 64 + lane;
    const int h0 = ht * 4;

    // 64 weight scalars + 4 biases -> SGPR file (uniform; readfirstlane exact)
    float wsc[4][16];
#pragma unroll
    for (int hh = 0; hh < 4; ++hh)
#pragma unroll
        for (int i = 0; i < 16; ++i)
            wsc[hh][i] = __builtin_amdgcn_readfirstlane(
                W1[(size_t)(h0 + hh) * NI + kq * 16 + i]);
    float bias[4];
#pragma unroll
    for (int hh = 0; hh < 4; ++hh)
        bias[hh] = __builtin_amdgcn_readfirstlane(b1[h0 + hh]);

    __shared__ float red[2][8][4][64];   // 16 KB: [parity][kq][hh][b-lane]

    const f32x4* __restrict__ xp =
        reinterpret_cast<const f32x4*>(x + (size_t)b * NT * NI + kq * 16);

    float v0 = 0.f, v1 = 0.f, v2 = 0.f, v3 = 0.f;  // LIF state (finisher)
#pragma unroll 1
    for (int t = 0; t < NT; ++t) {
        const f32x4 xq0 = xp[t * 32 + 0];
        const f32x4 xq1 = xp[t * 32 + 1];
        const f32x4 xq2 = xp[t * 32 + 2];
        const f32x4 xq3 = xp[t * 32 + 3];
        const int par = t & 1;
#pragma unroll
        for (int hh = 0; hh < 4; ++hh) {
            float a0 = 0.f, a1 = 0.f, a2 = 0.f, a3 = 0.f;
            a0 = fmaf(wsc[hh][0],  xq0[0], a0);
            a1 = fmaf(wsc[hh][1],  xq0[1], a1);
            a2 = fmaf(wsc[hh][2],  xq0[2], a2);
            a3 = fmaf(wsc[hh][3],  xq0[3], a3);
            a0 = fmaf(wsc[hh][4],  xq1[0], a0);
            a1 = fmaf(wsc[hh][5],  xq1[1], a1);
            a2 = fmaf(wsc[hh][6],  xq1[2], a2);
            a3 = fmaf(wsc[hh][7],  xq1[3], a3);
            a0 = fmaf(wsc[hh][8],  xq2[0], a0);
            a1 = fmaf(wsc[hh][9],  xq2[1], a1);
            a2 = fmaf(wsc[hh][10], xq2[2], a2);
            a3 = fmaf(wsc[hh][11], xq2[3], a3);
            a0 = fmaf(wsc[hh][12], xq3[0], a0);
            a1 = fmaf(wsc[hh][13], xq3[1], a1);
            a2 = fmaf(wsc[hh][14], xq3[2], a2);
            a3 = fmaf(wsc[hh][15], xq3[3], a3);
            red[par][kq][hh][lane] = (a0 + a1) + (a2 + a3);
        }
        __syncthreads();
        if (kq == 0) {
            // fixed kq order 0..7, pairwise -> deterministic
            float h1v[4];
#pragma unroll
            for (int hh = 0; hh < 4; ++hh) {
                const float r0 = red[par][0][hh][lane];
                const float r1 = red[par][1][hh][lane];
                const float r2 = red[par][2][hh][lane];
                const float r3 = red[par][3][hh][lane];
                const float r4 = red[par][4][hh][lane];
                const float r5 = red[par][5][hh][lane];
                const float r6 = red[par][6][hh][lane];
                const float r7 = red[par][7][hh][lane];
                h1v[hh] = (((r0 + r1) + (r2 + r3)) + ((r4 + r5) + (r6 + r7))) +
                          bias[hh];
            }
            // LIF per h (lane = b); ballot = b-mask for (t, h0+hh)
            v0 = fmaf(h1v[0] - v0, 0.5f, v0);
            v1 = fmaf(h1v[1] - v1, 0.5f, v1);
            v2 = fmaf(h1v[2] - v2, 0.5f, v2);
            v3 = fmaf(h1v[3] - v3, 0.5f, v3);
            const bool s0 = (v0 >= 1.0f), s1 = (v1 >= 1.0f);
            const bool s2 = (v2 >= 1.0f), s3 = (v3 >= 1.0f);
            v0 = s0 ? 0.f : v0;  v1 = s1 ? 0.f : v1;
            v2 = s2 ? 0.f : v2;  v3 = s3 ? 0.f : v3;
            const unsigned long long m0 = __ballot(s0);
            const unsigned long long m1 = __ballot(s1);
            const unsigned long long m2 = __ballot(s2);
            const unsigned long long m3 = __ballot(s3);
            if (lane == 0) {
                uint64_t* sw = sB + ((size_t)t * 2 + bh) * NH + h0;
                sw[0] = m0; sw[1] = m1; sw[2] = m2; sw[3] = m3;
            }
        }
        // red[par] slot re-written at t+2, after barrier(t+1): safe (proven).
    }
}

// ---------------------------------------------------------------------------
// bitT: 64x64 bit-transpose sB[t][bh][h] (b-masks per h) ->
// s1bits[t][b][hg] (h-masks per b). Wave per (t,bh); 16 hg iterations of
// 64 ballots; collect per-lane rows in padded LDS; final stores 128 B/lane.
// ---------------------------------------------------------------------------
__global__ __launch_bounds__(256) void snn_bitT(
    const uint64_t* __restrict__ sB, uint64_t* __restrict__ s1bits)
{
    __shared__ uint64_t tb[4][64][17];   // +1 u64 pad -> 2-lane/bank max
    const int wv = threadIdx.x >> 6;
    const int lane = threadIdx.x & 63;
    const int grp = blockIdx.x * 4 + wv;  // 0..4095
    const int t = grp >> 1;
    const int bh = grp & 1;

    const uint64_t* __restrict__ src = sB + ((size_t)t * 2 + bh) * NH;
#pragma unroll 1
    for (int hg = 0; hg < 16; ++hg) {
        const uint64_t w = src[hg * 64 + lane];  // bits over b, h = hg*64+lane
        uint64_t keep = 0;
#pragma unroll
        for (int j = 0; j < 64; ++j) {
            const unsigned long long m = __ballot((w >> j) & 1ull);
            keep = (lane == j) ? (uint64_t)m : keep;
        }
        tb[wv][lane][hg] = keep;  // lane holds h-mask for b = bh*64+lane
    }
    uint64_t* __restrict__ dst =
        s1bits + ((size_t)t * NB + bh * 64 + lane) * (NH / 64);
#pragma unroll
    for (int hg = 0; hg < 16; ++hg) dst[hg] = tb[wv][lane][hg];
}

// ---------------------------------------------------------------------------
// Phase B: sparse GEMM2 (proven). One wave per m = t*128+b row; per active
// spike one coalesced dwordx2 of W2P[k]. Sparse sum == dense sum exactly.
// ---------------------------------------------------------------------------
__global__ __launch_bounds__(256, 4) void snn_phaseB(
    const uint64_t* __restrict__ s1bits, const float2* __restrict__ W2P,
    float* __restrict__ h2)
{
    const int wv = threadIdx.x >> 6;
    const int lane = threadIdx.x & 63;
    const size_t m = (size_t)blockIdx.x * 4 + wv;  // 0..262143

    const uint64_t* __restrict__ sb = s1bits + m * (NH / 64);
    float a0 = 0.f, a1 = 0.f;

#pragma unroll 1
    for (int wd = 0; wd < NH / 64; ++wd) {
        const uint64_t m64 = sb[wd];
        const uint32_t mlo = (uint32_t)__builtin_amdgcn_readfirstlane((int)(uint32_t)m64);
        const uint32_t mhi = (uint32_t)__builtin_amdgcn_readfirstlane((int)(uint32_t)(m64 >> 32));
        uint64_t msk = ((uint64_t)mhi << 32) | mlo;
        while (msk) {
            const int i = __builtin_ctzll(msk);
            msk &= (msk - 1);
            const size_t k = ((size_t)wd << 6) + i;
            const float2 ww = W2P[k * 64 + lane];
            a0 += ww.x;
            a1 += ww.y;
        }
    }
    h2[m * NO + lane] = a0;
    h2[m * NO + 64 + lane] = a1;
}

// ---------------------------------------------------------------------------
// Phase D: LIF2 scan + decision-window count (proven).
// ---------------------------------------------------------------------------
__global__ __launch_bounds__(64) void snn_phaseD(
    const float* __restrict__ h2, const float* __restrict__ b2,
    float* __restrict__ out)
{
    const int idx = blockIdx.x * 64 + threadIdx.x;  // 0..16383
    const int b = idx >> 7;
    const int o = idx & 127;
    const float bias = b2[o];

    const float* __restrict__ p = h2 + (size_t)b * NO + o;
    float v = 0.f, c = 0.f;
#pragma unroll 16
    for (int t = 0; t < NT; ++t) {
        const float hh = p[(size_t)t * NB * NO] + bias;
        v = fmaf(hh - v, 0.5f, v);
        const bool s = (v >= 1.0f);
        v = s ? 0.f : v;
        if (t >= NT / 2) c += s ? 1.f : 0.f;
    }
    out[idx] = c;
}

extern "C" void kernel_launch(void* const* d_in, const int* in_sizes, int n_in,
                              void* d_out, int out_size, void* d_ws,
                              size_t ws_size, hipStream_t stream)
{
    const float* x  = (const float*)d_in[0];
    const float* W1 = (const float*)d_in[1];
    const float* b1 = (const float*)d_in[2];
    const float* W2 = (const float*)d_in[3];
    const float* b2 = (const float*)d_in[4];
    float* out = (float*)d_out;

    // ws layout (168.3 MB total, same as R8):
    //   [s1bits 33.55 MB][W2P 0.52 MB][h2 134.2 MB]
    // sB (33.55 MB) ALIASES the start of h2: sB lives A2->bitT; h2 lives B->D.
    uint8_t* ws = (uint8_t*)d_ws;
    uint64_t* s1bits = (uint64_t*)ws;
    float2* W2P = (float2*)(ws + (size_t)33554432);
    float* h2 = (float*)(ws + (size_t)33554432 + 524288);
    uint64_t* sB = (uint64_t*)(ws + (size_t)33554432 + 524288);  // alias

    w2p_kernel<<<dim3((NH * 64) / 256), dim3(256), 0, stream>>>(W2, W2P);
    snn_phaseA2<<<dim3(512), dim3(512), 0, stream>>>(x, W1, b1, sB);
    snn_bitT<<<dim3(1024), dim3(256), 0, stream>>>(sB, s1bits);
    snn_phaseB<<<dim3((NT * NB) / 4), dim3(256), 0, stream>>>(s1bits, W2P, h2);
    snn_phaseD<<<dim3(256), dim3(64), 0, stream>>>(h2, b2, out);
}

// Round 12
// 2318.606 us; speedup vs baseline: 1.8810x; 1.8810x over previous
//
#include <hip/hip_runtime.h>
#include <stdint.h>

#define NB 128
#define NT 2048
#define NI 128
#define NH 1024
#define NO 128

typedef float f32x4 __attribute__((ext_vector_type(4)));
typedef float f32x16 __attribute__((ext_vector_type(16)));

// ---------------------------------------------------------------------------
// W2P: pair-transpose W2 [O][H] -> W2P [H][64] of float2 {W2[j][k], W2[j+64][k]}
// ---------------------------------------------------------------------------
__global__ __launch_bounds__(256) void w2p_kernel(
    const float* __restrict__ W2, float2* __restrict__ W2P)
{
    const int idx = blockIdx.x * 256 + threadIdx.x;  // 0..65535
    const int k = idx >> 6;                          // 0..1023
    const int j = idx & 63;                          // 0..63
    W2P[idx] = make_float2(W2[(size_t)j * NH + k], W2[(size_t)(j + 64) * NH + k]);
}

// x 16-float chunk via SMEM scalar load (wave-uniform base, literal offset).
#define XL(DST, IMM)                                                      \
    asm volatile("s_load_dwordx16 %0, %1, " #IMM : "=s"(DST) : "s"(xb))

// 16 FMAs: one t's accumulator over 16 k (4 LDS weight quads), k ascending.
#define F16(ACC, XV)                                                      \
    do {                                                                  \
        ACC = fmaf(w0.x, (XV)[0],  ACC);                                  \
        ACC = fmaf(w0.y, (XV)[1],  ACC);                                  \
        ACC = fmaf(w0.z, (XV)[2],  ACC);                                  \
        ACC = fmaf(w0.w, (XV)[3],  ACC);                                  \
        ACC = fmaf(w1.x, (XV)[4],  ACC);                                  \
        ACC = fmaf(w1.y, (XV)[5],  ACC);                                  \
        ACC = fmaf(w1.z, (XV)[6],  ACC);                                  \
        ACC = fmaf(w1.w, (XV)[7],  ACC);                                  \
        ACC = fmaf(w2.x, (XV)[8],  ACC);                                  \
        ACC = fmaf(w2.y, (XV)[9],  ACC);                                  \
        ACC = fmaf(w2.z, (XV)[10], ACC);                                  \
        ACC = fmaf(w2.w, (XV)[11], ACC);                                  \
        ACC = fmaf(w3.x, (XV)[12], ACC);                                  \
        ACC = fmaf(w3.y, (XV)[13], ACC);                                  \
        ACC = fmaf(w3.z, (XV)[14], ACC);                                  \
        ACC = fmaf(w3.w, (XV)[15], ACC);                                  \
    } while (0)

// One 16-k chunk for 4 t's: 4 SMEM x loads + drain + 4 LDS weight quads
// (ds_read_b128, static imm off per-lane row base) + 64 FMA.
#define KCHUNK(Q0, I0, I1, I2, I3)                                        \
    {                                                                     \
        f32x16 xv0, xv1, xv2, xv3;                                        \
        XL(xv0, I0); XL(xv1, I1); XL(xv2, I2); XL(xv3, I3);               \
        asm volatile("s_waitcnt lgkmcnt(0)"                               \
                     : "+s"(xv0), "+s"(xv1), "+s"(xv2), "+s"(xv3));       \
        const f32x4 w0 = wrow[(Q0) + 0];                                  \
        const f32x4 w1 = wrow[(Q0) + 1];                                  \
        const f32x4 w2 = wrow[(Q0) + 2];                                  \
        const f32x4 w3 = wrow[(Q0) + 3];                                  \
        F16(t0, xv0); F16(t1, xv1); F16(t2, xv2); F16(t3, xv3);           \
    }

#define LIFSTEP(TT, TACC)                                                 \
    {                                                                     \
        const float h1 = ((TACC + red[par][0][TT][lane]) +                \
                          (red[par][1][TT][lane] + red[par][2][TT][lane])) + \
                         bias;                                            \
        v = fmaf(h1 - v, 0.5f, v);                                        \
        const bool sp = (v >= 1.0f);                                      \
        v = sp ? 0.0f : v;                                                \
        const unsigned long long m = __ballot(sp);                        \
        if (lane == 0) s1w[(size_t)TT * NB * (NH / 64)] = (uint64_t)m;    \
    }

// ---------------------------------------------------------------------------
// Phase A4: fused GEMM1 + LIF1. Weights in LDS (amortized 4x over t),
// x via SMEM, lane = h, k-quarter waves.
// grid = 2048 (128 b x 16 hg of 64 h), block = 256 = 4 waves = 4 k-quarters
// (32 k each) of the SAME 64 h (lane = h). LDS: wlds[64][33] f32x4 (33-slot
// pad -> (row+slot)%8 bank-group spread, 2-way = free) + red = 39 KB ->
// 4 blocks/CU = 4 waves/SIMD (hides SMEM drain latency; co-resident blocks
// share b -> K$ hits). Per 4t: 2 KCHUNKs (8 s_load_dwordx16, 8 ds_read_b128,
// 128 FMA per wave), then 4-way kq reduce via 2-slot-parity LDS (1 barrier),
// kq0 wave runs LIF + ballot + store for 4 t's. Only transient VGPR state.
// ---------------------------------------------------------------------------
__global__ __launch_bounds__(256, 4) void snn_phaseA4(
    const float* __restrict__ x, const float* __restrict__ W1,
    const float* __restrict__ b1, uint64_t* __restrict__ s1bits)
{
    const int b = blockIdx.x >> 4;      // 0..127
    const int hg = blockIdx.x & 15;     // 0..15
    const int kq = __builtin_amdgcn_readfirstlane(threadIdx.x >> 6);  // 0..3
    const int lane = threadIdx.x & 63;
    const int h = hg * 64 + lane;

    __shared__ f32x4 wlds[64][33];      // 33792 B, padded rows
    __shared__ float red[2][3][4][64];  // 6144 B: [parity][kq-1][tt][h-lane]

    // Stage W1 tile [64 h][128 k]: 2048 16B quads, coalesced per row.
#pragma unroll
    for (int i = 0; i < 8; ++i) {
        const int c = threadIdx.x + i * 256;  // 0..2047
        const int r = c >> 5;                 // 0..63
        const int kc = c & 31;                // k-quad 0..31
        wlds[r][kc] = *reinterpret_cast<const f32x4*>(
            W1 + (size_t)(hg * 64 + r) * NI + kc * 4);
    }
    __syncthreads();

    const float bias = b1[h];
    const f32x4* __restrict__ wrow = &wlds[lane][0];
    const int wb = kq * 8;              // this wave's quad base (k = kq*32)

    const float* xb = x + (size_t)b * NT * NI + kq * 32;
    uint64_t* s1w = s1bits + (size_t)b * (NH / 64) + hg;

    float v = 0.0f;
#pragma unroll 1
    for (int tc = 0; tc < NT; tc += 4) {
        float t0 = 0.f, t1 = 0.f, t2 = 0.f, t3 = 0.f;
        // imm = tt*512 + k16*64 bytes (x rows are 512 B; kq*128 in base)
        KCHUNK(wb + 0, 0x0,  0x200, 0x400, 0x600);
        KCHUNK(wb + 4, 0x40, 0x240, 0x440, 0x640);

        const int par = (tc >> 2) & 1;
        if (kq) {
            red[par][kq - 1][0][lane] = t0;
            red[par][kq - 1][1][lane] = t1;
            red[par][kq - 1][2][lane] = t2;
            red[par][kq - 1][3][lane] = t3;
        }
        __syncthreads();
        if (!kq) {
            LIFSTEP(0, t0);
            LIFSTEP(1, t1);
            LIFSTEP(2, t2);
            LIFSTEP(3, t3);
        }
        s1w += (size_t)4 * NB * (NH / 64);
        xb += 4 * NI;
        // red[par] slot re-written at tc+8, after barrier(tc+4): safe
        // (2-slot parity pattern proven R1/R5/R9).
    }
}

// ---------------------------------------------------------------------------
// Phase B: sparse GEMM2 (proven). One wave per m = t*128+b row; lane covers
// o = lane and o+64. Scalar ff1 loop over 16 mask words; per active k one
// coalesced dwordx2 of W2P[k]. Sparse sum (ascending k) == dense sum exactly.
// ---------------------------------------------------------------------------
__global__ __launch_bounds__(256, 4) void snn_phaseB(
    const uint64_t* __restrict__ s1bits, const float2* __restrict__ W2P,
    float* __restrict__ h2)
{
    const int wv = threadIdx.x >> 6;
    const int lane = threadIdx.x & 63;
    const size_t m = (size_t)blockIdx.x * 4 + wv;  // 0..262143

    const uint64_t* __restrict__ sb = s1bits + m * (NH / 64);
    float a0 = 0.f, a1 = 0.f;

#pragma unroll 1
    for (int wd = 0; wd < NH / 64; ++wd) {
        const uint64_t m64 = sb[wd];
        const uint32_t mlo = (uint32_t)__builtin_amdgcn_readfirstlane((int)(uint32_t)m64);
        const uint32_t mhi = (uint32_t)__builtin_amdgcn_readfirstlane((int)(uint32_t)(m64 >> 32));
        uint64_t msk = ((uint64_t)mhi << 32) | mlo;
        while (msk) {
            const int i = __builtin_ctzll(msk);
            msk &= (msk - 1);
            const size_t k = ((size_t)wd << 6) + i;
            const float2 ww = W2P[k * 64 + lane];
            a0 += ww.x;
            a1 += ww.y;
        }
    }
    h2[m * NO + lane] = a0;
    h2[m * NO + 64 + lane] = a1;
}

// ---------------------------------------------------------------------------
// Phase D: LIF2 scan + decision-window count (proven).
// ---------------------------------------------------------------------------
__global__ __launch_bounds__(64) void snn_phaseD(
    const float* __restrict__ h2, const float* __restrict__ b2,
    float* __restrict__ out)
{
    const int idx = blockIdx.x * 64 + threadIdx.x;  // 0..16383
    const int b = idx >> 7;
    const int o = idx & 127;
    const float bias = b2[o];

    const float* __restrict__ p = h2 + (size_t)b * NO + o;
    float v = 0.f, c = 0.f;
#pragma unroll 16
    for (int t = 0; t < NT; ++t) {
        const float hh = p[(size_t)t * NB * NO] + bias;
        v = fmaf(hh - v, 0.5f, v);
        const bool s = (v >= 1.0f);
        v = s ? 0.f : v;
        if (t >= NT / 2) c += s ? 1.f : 0.f;
    }
    out[idx] = c;
}

extern "C" void kernel_launch(void* const* d_in, const int* in_sizes, int n_in,
                              void* d_out, int out_size, void* d_ws,
                              size_t ws_size, hipStream_t stream)
{
    const float* x  = (const float*)d_in[0];
    const float* W1 = (const float*)d_in[1];
    const float* b1 = (const float*)d_in[2];
    const float* W2 = (const float*)d_in[3];
    const float* b2 = (const float*)d_in[4];
    float* out = (float*)d_out;

    // ws layout: [s1bits 33.55 MB][W2P 0.52 MB][h2 134.2 MB]
    uint8_t* ws = (uint8_t*)d_ws;
    uint64_t* s1bits = (uint64_t*)ws;
    float2* W2P = (float2*)(ws + (size_t)NT * NB * (NH / 64) * 8);
    float* h2 = (float*)(ws + (size_t)NT * NB * (NH / 64) * 8 +
                         (size_t)NH * 64 * sizeof(float2));

    w2p_kernel<<<dim3((NH * 64) / 256), dim3(256), 0, stream>>>(W2, W2P);
    snn_phaseA4<<<dim3(NB * 16), dim3(256), 0, stream>>>(x, W1, b1, s1bits);
    snn_phaseB<<<dim3((NT * NB) / 4), dim3(256), 0, stream>>>(s1bits, W2P, h2);
    snn_phaseD<<<dim3(256), dim3(64), 0, stream>>>(h2, b2, out);
}